// Round 7
// baseline (3268.251 us; speedup 1.0000x reference)
//
#include <hip/hip_runtime.h>

// ---- problem constants ----
#define BB 64
#define TLEN 256
#define HH 512
#define GG 1536     // 3*H
#define EPAD 320    // E=300 padded to mult of 64
#define NN 3072     // 2*G (both directions stacked)
#define MM 16384    // T*B

typedef __attribute__((ext_vector_type(8))) __fp16 half8;
typedef __attribute__((ext_vector_type(4))) __fp16 half4;
typedef __attribute__((ext_vector_type(4))) float floatx4;

typedef union { unsigned long long u[2]; half8 v; } hpack;
typedef union { half4 h4; unsigned long long u; } hpack4;

// ---- fused prep: padw (blocks 0..959) | cvt (960..2495) | embed (2496..7615) ----
__global__ __launch_bounds__(256) void g2_prep(const int* __restrict__ x,
                                               const float* __restrict__ emb,
                                               __fp16* __restrict__ e,
                                               const float* __restrict__ w_ih0,
                                               __fp16* __restrict__ w0p,
                                               const float* __restrict__ w_ih1,
                                               __fp16* __restrict__ w1c) {
  const int blk = blockIdx.x;
  if (blk < 960) {                       // pad+convert w_ih0 [3072,300]->[3072,320]
    int idx = blk * 256 + threadIdx.x;   // total 3072*80
    int row = idx / 80;
    int c = idx - row * 80;
    half4 v = {0, 0, 0, 0};
    if (c < 75) {
      float4 f = *(const float4*)&w_ih0[(long)row * 300 + c * 4];
      v[0] = (__fp16)f.x; v[1] = (__fp16)f.y; v[2] = (__fp16)f.z; v[3] = (__fp16)f.w;
    }
    *(half4*)&w0p[row * EPAD + c * 4] = v;
  } else if (blk < 2496) {               // bulk fp32->fp16 of w_ih1 [3072,1024]
    long idx = (long)(blk - 960) * 256 + threadIdx.x;
    float4 a = *(const float4*)&w_ih1[idx * 8];
    float4 b = *(const float4*)&w_ih1[idx * 8 + 4];
    half8 o;
    o[0] = (__fp16)a.x; o[1] = (__fp16)a.y; o[2] = (__fp16)a.z; o[3] = (__fp16)a.w;
    o[4] = (__fp16)b.x; o[5] = (__fp16)b.y; o[6] = (__fp16)b.z; o[7] = (__fp16)b.w;
    *(half8*)&w1c[idx * 8] = o;
  } else {                               // embedding gather + K-pad + cvt
    int idx = (blk - 2496) * 256 + threadIdx.x;   // total 16384*80
    int row = idx / 80;
    int c = idx - row * 80;
    int t = row >> 6, b = row & 63;
    half4 v = {0, 0, 0, 0};
    if (c < 75) {
      int xi = x[b * TLEN + t];
      float4 f = *(const float4*)&emb[(long)xi * 300 + c * 4];
      v[0] = (__fp16)f.x; v[1] = (__fp16)f.y; v[2] = (__fp16)f.z; v[3] = (__fp16)f.w;
    }
    *(half4*)&e[row * EPAD + c * 4] = v;
  }
}

// ---- TN GEMM: C[M,N] fp16 = A[M,Kp] fp16 x W[N,Kp] fp16^T + bias[N](fp32) ----
__global__ __launch_bounds__(256) void g2_gemm(const __fp16* __restrict__ A,
                                               const __fp16* __restrict__ W,
                                               const float* __restrict__ bias,
                                               __fp16* __restrict__ C,
                                               int M, int N, int Kp) {
  __shared__ __fp16 As[128][72];
  __shared__ __fp16 Ws[128][72];
  const int nTiles = N >> 7;
  const int m0 = (blockIdx.x / nTiles) << 7;
  const int n0 = (blockIdx.x % nTiles) << 7;
  const int tid = threadIdx.x;
  const int lane = tid & 63, wv = tid >> 6;
  const int wm = (wv >> 1) << 6, wn = (wv & 1) << 6;
  const int nsub = lane & 15, quad = lane >> 4;

  floatx4 acc[4][4];
#pragma unroll
  for (int i = 0; i < 4; i++)
#pragma unroll
    for (int j = 0; j < 4; j++) acc[i][j] = (floatx4){0.f, 0.f, 0.f, 0.f};

  const int lr = tid >> 3;          // 0..31
  const int lc = (tid & 7) << 3;    // 0..56 step 8
  for (int ko = 0; ko < Kp; ko += 64) {
#pragma unroll
    for (int p = 0; p < 4; p++) {
      int r = lr + p * 32;
      *(half8*)&As[r][lc] = *(const half8*)&A[(long)(m0 + r) * Kp + ko + lc];
      *(half8*)&Ws[r][lc] = *(const half8*)&W[(long)(n0 + r) * Kp + ko + lc];
    }
    __syncthreads();
#pragma unroll
    for (int kk = 0; kk < 64; kk += 32) {
      half8 af[4], bf[4];
      const int kr = kk + (quad << 3);
#pragma unroll
      for (int i = 0; i < 4; i++) af[i] = *(const half8*)&As[wm + i * 16 + nsub][kr];
#pragma unroll
      for (int j = 0; j < 4; j++) bf[j] = *(const half8*)&Ws[wn + j * 16 + nsub][kr];
#pragma unroll
      for (int i = 0; i < 4; i++)
#pragma unroll
        for (int j = 0; j < 4; j++)
          acc[i][j] = __builtin_amdgcn_mfma_f32_16x16x32_f16(af[i], bf[j], acc[i][j], 0, 0, 0);
    }
    __syncthreads();
  }
#pragma unroll
  for (int j = 0; j < 4; j++) {
    int col = n0 + wn + j * 16 + nsub;
    float bv = bias[col];
#pragma unroll
    for (int i = 0; i < 4; i++) {
      int rb = m0 + wm + i * 16 + (quad << 2);
#pragma unroll
      for (int ii = 0; ii < 4; ii++)
        C[(long)(rb + ii) * N + col] = (__fp16)(acc[i][j][ii] + bv);
    }
  }
}

// ---- persistent bidirectional GRU recurrence: wave-autonomous, DATA-AS-FLAG ----
// grid 64 WGs x 256 thr. Wave = (dir d, group g, batch-half mb of 16 rows,
// unit-tile ut of 16 units). NO __syncthreads / NO fences / NO FLAGS in the
// step loop. Sync = sentinel-validated data spin (round-6 proven):
//   * hx exchange buffer [t][d][g][mb], 16 KB blocks in MFMA-fragment order,
//     pre-memset 0xFF (fp16 0xFFFF = -NaN, unreachable since |h| <= 1).
//     Every address written EXACTLY ONCE via 8B relaxed agent-scope atomic
//     stores (single LLC txn, appears atomically).
//   * consumers use 8B relaxed agent-scope atomic loads + sentinel validation
//     with retry. Data IS the flag; no store->load ordering assumed anywhere.
//   * NEW (r7): first-attempt loads for step s+1 are issued straight-line,
//     unconditionally, immediately after publishing step s — the LLC round
//     trip overlaps the loop tail/top, so the common-case check needs zero
//     extra rounds; the branchy masked reload only runs for stragglers.
//   * NEW (r7): each gate accumulator split into even/odd-kk chains (6 accs,
//     8-deep) — halves exposed MFMA dependent latency at 1 wave/SIMD.
//   * h_old in 4 VGPRs; W_hh fragments in ~192 VGPRs (__launch_bounds__(256,1));
//     publish transpose via wave-local LDS bounce (in-order DS pipe; compiler
//     barrier + same-elem-type half4 read — TBAA lesson from rounds 1/3/4).
__global__ __launch_bounds__(256, 1) void g2_rnn(const float* __restrict__ whh,  // [2][1536][512] fp32
                                                 const float* __restrict__ bhh,  // [2][1536] fp32
                                                 const __fp16* __restrict__ xp,  // [256][64][3072]
                                                 __fp16* __restrict__ hout,      // [256][64][1024]
                                                 __fp16* __restrict__ hx) {      // [256][2][2][2][8192] (pre-memset 0xFF)
  __shared__ __fp16 Wl[96][520];    // staging for weight load/convert (init only)
  __shared__ __fp16 hst[4][16][20]; // per-wave publish transpose buffer
  const unsigned long long SENT = 0xFFFFFFFFFFFFFFFFULL;
  const int bid = blockIdx.x;
  const int gi = bid & 3;           // d*2+g
  const int uo = bid >> 2;          // 0..15 unit-tile-pair index
  const int d = gi >> 1, g = gi & 1;
  const int tid = threadIdx.x;
  const int lane = tid & 63, wv = tid >> 6;
  const int U0 = uo << 5;           // 32 units per WG
  const int mb = wv & 1, ut = wv >> 1;
  const int nsub = lane & 15, quad = lane >> 4;
  const int bq = (g << 5) + (mb << 4);   // wave's global batch base (16 rows)
  const int ul = (ut << 4) + nsub;       // wave's unit (local 0..31)

  // ---- one-time: load + convert weights [3 gates][32 units][512] into LDS ----
  const float* wd = whh + (long)d * (GG * HH);
  for (int idx = tid; idx < 96 * 64; idx += 256) {
    int r = idx >> 6;               // 0..95
    int c = (idx & 63) << 3;        // 0..504 step 8
    int gate = r >> 5, u2 = r & 31;
    const float* src = &wd[(long)(gate * HH + U0 + u2) * HH + c];
    float4 a = *(const float4*)&src[0];
    float4 b = *(const float4*)&src[4];
    half8 o;
    o[0] = (__fp16)a.x; o[1] = (__fp16)a.y; o[2] = (__fp16)a.z; o[3] = (__fp16)a.w;
    o[4] = (__fp16)b.x; o[5] = (__fp16)b.y; o[6] = (__fp16)b.z; o[7] = (__fp16)b.w;
    *(half8*)&Wl[r][c] = o;
  }
  __syncthreads();

  // ---- hoist this wave's weight fragments into registers: 48 x half8 ----
  half8 wr_[16], wz_[16], wn_[16];
#pragma unroll
  for (int kk = 0; kk < 16; kk++) {
    const int kcol = (kk << 5) + (quad << 3);
    wr_[kk] = *(const half8*)&Wl[ul][kcol];
    wz_[kk] = *(const half8*)&Wl[32 + ul][kcol];
    wn_[kk] = *(const half8*)&Wl[64 + ul][kcol];
  }

  const float bhr = bhh[d * GG + U0 + ul];
  const float bhz = bhh[d * GG + HH + U0 + ul];
  const float bhn = bhh[d * GG + 2 * HH + U0 + ul];

  // consumer per-lane ULL index within a 16KB hx block (per kk: +kk*128)
  const int cidx = ((quad >> 1) << 6) + (nsub << 2) + ((quad & 1) << 1);
  // producer per-lane ULL index: elem = uo*512 + ut*256 + r*16 + c4
  const int pr = lane & 15, pc4 = (lane >> 4) << 2;
  const int pidx = (uo << 7) + (ut << 6) + (pr << 2) + (pc4 >> 2);

  float hprev[4] = {0.f, 0.f, 0.f, 0.f};
  hpack u[16];                      // loop-carried first-attempt buffer

  for (int s = 0; s < TLEN; s++) {
    const int tt = d ? (TLEN - 1 - s) : s;
    // prefetch xp for this step (overlaps the in-flight hx first attempt)
    float xr[4], xz[4], xn[4];
    {
      const __fp16* xb0 = xp + (long)(tt * BB) * NN + d * GG + U0 + ul;
#pragma unroll
      for (int i = 0; i < 4; i++) {
        const __fp16* xb = xb0 + (long)(bq + (quad << 2) + i) * NN;
        xr[i] = (float)xb[0];
        xz[i] = (float)xb[HH];
        xn[i] = (float)xb[2 * HH];
      }
    }
    floatx4 ar0 = {0.f, 0.f, 0.f, 0.f}, ar1 = ar0, az0 = ar0, az1 = ar0, an0 = ar0, an1 = ar0;
    if (s > 0) {
      const int pt = d ? (tt + 1) : (tt - 1);
      const unsigned long long* hx8 =
          (const unsigned long long*)(hx + ((((long)pt * 2 + d) * 2 + g) * 2 + mb) * 8192);
      // validate the pipelined first attempt; masked retry for stragglers only
      unsigned inv = 0;
#pragma unroll
      for (int kk = 0; kk < 16; kk++) {
        inv |= (u[kk].u[0] == SENT) ? (1u << (2 * kk)) : 0u;
        inv |= (u[kk].u[1] == SENT) ? (1u << (2 * kk + 1)) : 0u;
      }
      while (__any(inv != 0)) {
#pragma unroll
        for (int kk = 0; kk < 16; kk++) {
          if (inv & (1u << (2 * kk)))
            u[kk].u[0] = __hip_atomic_load(&hx8[kk * 128 + cidx], __ATOMIC_RELAXED, __HIP_MEMORY_SCOPE_AGENT);
          if (inv & (1u << (2 * kk + 1)))
            u[kk].u[1] = __hip_atomic_load(&hx8[kk * 128 + cidx + 1], __ATOMIC_RELAXED, __HIP_MEMORY_SCOPE_AGENT);
        }
        unsigned ninv = 0;
#pragma unroll
        for (int kk = 0; kk < 16; kk++) {
          ninv |= (u[kk].u[0] == SENT) ? (1u << (2 * kk)) : 0u;
          ninv |= (u[kk].u[1] == SENT) ? (1u << (2 * kk + 1)) : 0u;
        }
        inv = ninv;
      }
      // 6 accumulator chains (8-deep each) — halves exposed MFMA latency
#pragma unroll
      for (int kk = 0; kk < 16; kk += 2) {
        ar0 = __builtin_amdgcn_mfma_f32_16x16x32_f16(u[kk].v, wr_[kk], ar0, 0, 0, 0);
        az0 = __builtin_amdgcn_mfma_f32_16x16x32_f16(u[kk].v, wz_[kk], az0, 0, 0, 0);
        an0 = __builtin_amdgcn_mfma_f32_16x16x32_f16(u[kk].v, wn_[kk], an0, 0, 0, 0);
        ar1 = __builtin_amdgcn_mfma_f32_16x16x32_f16(u[kk + 1].v, wr_[kk + 1], ar1, 0, 0, 0);
        az1 = __builtin_amdgcn_mfma_f32_16x16x32_f16(u[kk + 1].v, wz_[kk + 1], az1, 0, 0, 0);
        an1 = __builtin_amdgcn_mfma_f32_16x16x32_f16(u[kk + 1].v, wn_[kk + 1], an1, 0, 0, 0);
      }
    }
    // epilogue: gates in fp32; h_old in registers (same lane wrote it)
#pragma unroll
    for (int i = 0; i < 4; i++) {
      float grv = ar0[i] + ar1[i] + xr[i] + bhr;
      float gzv = az0[i] + az1[i] + xz[i] + bhz;
      float gnv = an0[i] + an1[i] + bhn;        // recurrent part of n-gate (+b_hh)
      float rg = 1.f / (1.f + __expf(-grv));
      float zg = 1.f / (1.f + __expf(-gzv));
      float ex = __expf(2.f * (xn[i] + rg * gnv));
      float ng = 1.f - 2.f / (ex + 1.f);        // tanh
      float hv = (1.f - zg) * ng + zg * hprev[i];
      hprev[i] = hv;
      hst[wv][(quad << 2) + i][nsub] = (__fp16)hv;   // wave-local transpose stage
    }
    // COMPILER barrier: keep all hst DS writes before the DS read below
    // (DS pipe is in-order per wave; only IR ordering must be pinned).
    asm volatile("" ::: "memory");
    // publish own 16x16 tile: hx (exchange) via 8B atomic store — the wave's
    // 64 lanes cover 512 consecutive bytes; hout (standard layout) via plain
    // cached store, consumed only after kernel end.
    {
      hpack4 pk;
      pk.h4 = *(const half4*)&hst[wv][pr][pc4];
      unsigned long long* hxw =
          (unsigned long long*)(hx + ((((long)tt * 2 + d) * 2 + g) * 2 + mb) * 8192);
      __hip_atomic_store(&hxw[pidx], pk.u, __ATOMIC_RELAXED, __HIP_MEMORY_SCOPE_AGENT);
      *(half4*)&hout[(long)(tt * BB + (g << 5) + (mb << 4) + pr) * 1024 +
                     d * HH + U0 + (ut << 4) + pc4] = pk.h4;
    }
    // pipelined FIRST ATTEMPT for step s+1: straight-line unconditional loads
    // of the block the domain is publishing right now (t = tt). By the check
    // at the top of s+1, the LLC round trip has already elapsed.
    if (s + 1 < TLEN) {
      const unsigned long long* hx8n =
          (const unsigned long long*)(hx + ((((long)tt * 2 + d) * 2 + g) * 2 + mb) * 8192);
#pragma unroll
      for (int kk = 0; kk < 16; kk++) {
        u[kk].u[0] = __hip_atomic_load(&hx8n[kk * 128 + cidx], __ATOMIC_RELAXED, __HIP_MEMORY_SCOPE_AGENT);
        u[kk].u[1] = __hip_atomic_load(&hx8n[kk * 128 + cidx + 1], __ATOMIC_RELAXED, __HIP_MEMORY_SCOPE_AGENT);
      }
    }
  }
}

// ---- max-pool over T ----
__global__ __launch_bounds__(256) void g2_pool(const __fp16* __restrict__ h1,
                                               float* __restrict__ pooled) {
  int b = blockIdx.x;
  int j0 = threadIdx.x * 4;
  float m[4] = {-3e38f, -3e38f, -3e38f, -3e38f};
  const __fp16* p = h1 + b * 1024 + j0;
  for (int t = 0; t < TLEN; t++) {
    half4 v = *(const half4*)(p + (long)t * BB * 1024);
#pragma unroll
    for (int q = 0; q < 4; q++) m[q] = fmaxf(m[q], (float)v[q]);
  }
  float* o = pooled + b * 1024 + j0;
#pragma unroll
  for (int q = 0; q < 4; q++) o[q] = m[q];
}

// ---- classifier head (all fp32) ----
__global__ __launch_bounds__(128) void g2_head(const float* __restrict__ pooled,
                                               const float* __restrict__ w1,
                                               const float* __restrict__ b1,
                                               const float* __restrict__ w2,
                                               const float* __restrict__ b2,
                                               float* __restrict__ out) {
  __shared__ float pl[1024];
  __shared__ float hid[128];
  int b = blockIdx.x, j = threadIdx.x;
  for (int k = j; k < 1024; k += 128) pl[k] = pooled[b * 1024 + k];
  __syncthreads();
  float acc = b1[j];
  const float* wr = w1 + (long)j * 1024;
  for (int k = 0; k < 1024; k += 4) {
    float4 w = *(const float4*)&wr[k];
    acc += pl[k] * w.x + pl[k + 1] * w.y + pl[k + 2] * w.z + pl[k + 3] * w.w;
  }
  hid[j] = fmaxf(acc, 0.f);
  __syncthreads();
  if (j < 2) {
    float a = b2[j];
    for (int k = 0; k < 128; k++) a += hid[k] * w2[j * 128 + k];
    out[b * 2 + j] = a;
  }
}

extern "C" void kernel_launch(void* const* d_in, const int* in_sizes, int n_in,
                              void* d_out, int out_size, void* d_ws, size_t ws_size,
                              hipStream_t stream) {
  (void)in_sizes; (void)n_in; (void)out_size; (void)ws_size;
  const int* x = (const int*)d_in[0];
  const float* emb = (const float*)d_in[1];
  const float* w_ih0 = (const float*)d_in[2];
  const float* w_hh0 = (const float*)d_in[3];
  const float* b_ih0 = (const float*)d_in[4];
  const float* b_hh0 = (const float*)d_in[5];
  const float* w_ih1 = (const float*)d_in[6];
  const float* w_hh1 = (const float*)d_in[7];
  const float* b_ih1 = (const float*)d_in[8];
  const float* b_hh1 = (const float*)d_in[9];
  const float* w1 = (const float*)d_in[10];
  const float* b1 = (const float*)d_in[11];
  const float* w2 = (const float*)d_in[12];
  const float* b2 = (const float*)d_in[13];

  // ---- workspace layout (total <= 186,785,792 B, unchanged) ----
  // hx exchange buffers ALIAS the dead h-region of the other layer:
  //   rnn0: hout=h0, hx=h1 region (h1 dead until rnn1 writes it)
  //   rnn1: hout=h1, hx=h0 region (h0 dead after gemm1 consumed it)
  char* ws = (char*)d_ws;
  __fp16* xp = (__fp16*)(ws + 0);                  // 16384*3072*2 = 100,663,296
  __fp16* h0 = (__fp16*)(ws + 100663296);          // 16384*1024*2 =  33,554,432
  __fp16* h1 = (__fp16*)(ws + 134217728);          //                 33,554,432
  __fp16* e_pad = (__fp16*)(ws + 167772160);       // 16384*320*2  =  10,485,760
  __fp16* w0p = (__fp16*)(ws + 178257920);         // 3072*320*2   =   1,966,080
  __fp16* w1c = (__fp16*)(ws + 180224000);         // 3072*1024*2  =   6,291,456
  float* pooled = (float*)(ws + 186515456);        // 64*1024*4    =     262,144

  // sentinel-fill hx for rnn0 (= h1 region): 0xFFFF per fp16 = -NaN
  (void)hipMemsetAsync(h1, 0xFF, 33554432, stream);
  g2_prep<<<7616, 256, 0, stream>>>(x, emb, e_pad, w_ih0, w0p, w_ih1, w1c);
  g2_gemm<<<3072, 256, 0, stream>>>(e_pad, w0p, b_ih0, xp, MM, NN, EPAD);
  g2_rnn<<<64, 256, 0, stream>>>(w_hh0, b_hh0, xp, h0, h1);
  g2_gemm<<<3072, 256, 0, stream>>>(h0, w1c, b_ih1, xp, MM, NN, 1024);
  // h0 now dead -> becomes hx for rnn1 (stream-ordered after gemm consumed it)
  (void)hipMemsetAsync(h0, 0xFF, 33554432, stream);
  g2_rnn<<<64, 256, 0, stream>>>(w_hh1, b_hh1, xp, h1, h0);
  g2_pool<<<64, 256, 0, stream>>>(h1, pooled);
  g2_head<<<64, 128, 0, stream>>>(pooled, w1, b1, w2, b2, (float*)d_out);
}

// Round 8
// 2045.516 us; speedup vs baseline: 1.5978x; 1.5978x over previous
//
#include <hip/hip_runtime.h>

// ---- problem constants ----
#define BB 64
#define TLEN 256
#define HH 512
#define GG 1536     // 3*H
#define EPAD 320    // E=300 padded to mult of 64
#define NN 3072     // 2*G (both directions stacked)
#define MM 16384    // T*B

typedef __attribute__((ext_vector_type(8))) __fp16 half8;
typedef __attribute__((ext_vector_type(4))) __fp16 half4;
typedef __attribute__((ext_vector_type(4))) float floatx4;

typedef union { unsigned long long u[2]; half8 v; } hpack;
typedef union { half4 h4; unsigned long long u; } hpack4;

// ---- fused prep: padw (blocks 0..959) | cvt (960..2495) | embed (2496..7615) ----
__global__ __launch_bounds__(256) void g2_prep(const int* __restrict__ x,
                                               const float* __restrict__ emb,
                                               __fp16* __restrict__ e,
                                               const float* __restrict__ w_ih0,
                                               __fp16* __restrict__ w0p,
                                               const float* __restrict__ w_ih1,
                                               __fp16* __restrict__ w1c) {
  const int blk = blockIdx.x;
  if (blk < 960) {                       // pad+convert w_ih0 [3072,300]->[3072,320]
    int idx = blk * 256 + threadIdx.x;   // total 3072*80
    int row = idx / 80;
    int c = idx - row * 80;
    half4 v = {0, 0, 0, 0};
    if (c < 75) {
      float4 f = *(const float4*)&w_ih0[(long)row * 300 + c * 4];
      v[0] = (__fp16)f.x; v[1] = (__fp16)f.y; v[2] = (__fp16)f.z; v[3] = (__fp16)f.w;
    }
    *(half4*)&w0p[row * EPAD + c * 4] = v;
  } else if (blk < 2496) {               // bulk fp32->fp16 of w_ih1 [3072,1024]
    long idx = (long)(blk - 960) * 256 + threadIdx.x;
    float4 a = *(const float4*)&w_ih1[idx * 8];
    float4 b = *(const float4*)&w_ih1[idx * 8 + 4];
    half8 o;
    o[0] = (__fp16)a.x; o[1] = (__fp16)a.y; o[2] = (__fp16)a.z; o[3] = (__fp16)a.w;
    o[4] = (__fp16)b.x; o[5] = (__fp16)b.y; o[6] = (__fp16)b.z; o[7] = (__fp16)b.w;
    *(half8*)&w1c[idx * 8] = o;
  } else {                               // embedding gather + K-pad + cvt
    int idx = (blk - 2496) * 256 + threadIdx.x;   // total 16384*80
    int row = idx / 80;
    int c = idx - row * 80;
    int t = row >> 6, b = row & 63;
    half4 v = {0, 0, 0, 0};
    if (c < 75) {
      int xi = x[b * TLEN + t];
      float4 f = *(const float4*)&emb[(long)xi * 300 + c * 4];
      v[0] = (__fp16)f.x; v[1] = (__fp16)f.y; v[2] = (__fp16)f.z; v[3] = (__fp16)f.w;
    }
    *(half4*)&e[row * EPAD + c * 4] = v;
  }
}

// ---- TN GEMM: C[M,N] fp16 = A[M,Kp] fp16 x W[N,Kp] fp16^T + bias[N](fp32) ----
__global__ __launch_bounds__(256) void g2_gemm(const __fp16* __restrict__ A,
                                               const __fp16* __restrict__ W,
                                               const float* __restrict__ bias,
                                               __fp16* __restrict__ C,
                                               int M, int N, int Kp) {
  __shared__ __fp16 As[128][72];
  __shared__ __fp16 Ws[128][72];
  const int nTiles = N >> 7;
  const int m0 = (blockIdx.x / nTiles) << 7;
  const int n0 = (blockIdx.x % nTiles) << 7;
  const int tid = threadIdx.x;
  const int lane = tid & 63, wv = tid >> 6;
  const int wm = (wv >> 1) << 6, wn = (wv & 1) << 6;
  const int nsub = lane & 15, quad = lane >> 4;

  floatx4 acc[4][4];
#pragma unroll
  for (int i = 0; i < 4; i++)
#pragma unroll
    for (int j = 0; j < 4; j++) acc[i][j] = (floatx4){0.f, 0.f, 0.f, 0.f};

  const int lr = tid >> 3;          // 0..31
  const int lc = (tid & 7) << 3;    // 0..56 step 8
  for (int ko = 0; ko < Kp; ko += 64) {
#pragma unroll
    for (int p = 0; p < 4; p++) {
      int r = lr + p * 32;
      *(half8*)&As[r][lc] = *(const half8*)&A[(long)(m0 + r) * Kp + ko + lc];
      *(half8*)&Ws[r][lc] = *(const half8*)&W[(long)(n0 + r) * Kp + ko + lc];
    }
    __syncthreads();
#pragma unroll
    for (int kk = 0; kk < 64; kk += 32) {
      half8 af[4], bf[4];
      const int kr = kk + (quad << 3);
#pragma unroll
      for (int i = 0; i < 4; i++) af[i] = *(const half8*)&As[wm + i * 16 + nsub][kr];
#pragma unroll
      for (int j = 0; j < 4; j++) bf[j] = *(const half8*)&Ws[wn + j * 16 + nsub][kr];
#pragma unroll
      for (int i = 0; i < 4; i++)
#pragma unroll
        for (int j = 0; j < 4; j++)
          acc[i][j] = __builtin_amdgcn_mfma_f32_16x16x32_f16(af[i], bf[j], acc[i][j], 0, 0, 0);
    }
    __syncthreads();
  }
#pragma unroll
  for (int j = 0; j < 4; j++) {
    int col = n0 + wn + j * 16 + nsub;
    float bv = bias[col];
#pragma unroll
    for (int i = 0; i < 4; i++) {
      int rb = m0 + wm + i * 16 + (quad << 2);
#pragma unroll
      for (int ii = 0; ii < 4; ii++)
        C[(long)(rb + ii) * N + col] = (__fp16)(acc[i][j][ii] + bv);
    }
  }
}

// ---- persistent bidirectional GRU recurrence: wave-autonomous, DATA-AS-FLAG ----
// grid 64 WGs x 256 thr. Wave = (dir d, group g, batch-half mb of 16 rows,
// unit-tile ut of 16 units). NO __syncthreads / NO fences / NO FLAGS in the
// step loop. Sync = sentinel-validated data spin (round-6 proven):
//   * hx exchange buffer [t][d][g][mb], 16 KB blocks in MFMA-fragment order,
//     pre-memset 0xFF (fp16 0xFFFF = -NaN, unreachable since |h| <= 1).
//     Every address written EXACTLY ONCE via 8B relaxed agent-scope atomic
//     stores (single LLC txn, appears atomically — never torn).
//   * consumers use 8B relaxed agent-scope atomic loads + sentinel validation
//     with retry. Data IS the flag; no store->load ordering assumed anywhere.
//   * SPIN TIMING (round-7 lesson): the first attempt must sit at the TOP of
//     the consuming step (after xp issue) — one loop-boundary of slack for
//     the other 31 producers. Prefetching at publish time guarantees misses
//     and a mandatory retry round every step (round 7: 920 -> 1485 µs).
//   * retry rounds are UNCONDITIONAL full 32-load rounds — no per-word
//     exec-mask branches (round 6's masked path), fully coalesced each round.
//   * 6 MFMA accumulator chains (even/odd kk) halve exposed dependent latency.
//   * h_old in 4 VGPRs; W_hh fragments in ~192 VGPRs (__launch_bounds__(256,1));
//     publish transpose via wave-local LDS bounce (in-order DS pipe; compiler
//     barrier + same-elem-type half4 read — TBAA lesson from rounds 1/3/4).
__global__ __launch_bounds__(256, 1) void g2_rnn(const float* __restrict__ whh,  // [2][1536][512] fp32
                                                 const float* __restrict__ bhh,  // [2][1536] fp32
                                                 const __fp16* __restrict__ xp,  // [256][64][3072]
                                                 __fp16* __restrict__ hout,      // [256][64][1024]
                                                 __fp16* __restrict__ hx) {      // [256][2][2][2][8192] (pre-memset 0xFF)
  __shared__ __fp16 Wl[96][520];    // staging for weight load/convert (init only)
  __shared__ __fp16 hst[4][16][20]; // per-wave publish transpose buffer
  const unsigned long long SENT = 0xFFFFFFFFFFFFFFFFULL;
  const int bid = blockIdx.x;
  const int gi = bid & 3;           // d*2+g
  const int uo = bid >> 2;          // 0..15 unit-tile-pair index
  const int d = gi >> 1, g = gi & 1;
  const int tid = threadIdx.x;
  const int lane = tid & 63, wv = tid >> 6;
  const int U0 = uo << 5;           // 32 units per WG
  const int mb = wv & 1, ut = wv >> 1;
  const int nsub = lane & 15, quad = lane >> 4;
  const int bq = (g << 5) + (mb << 4);   // wave's global batch base (16 rows)
  const int ul = (ut << 4) + nsub;       // wave's unit (local 0..31)

  // ---- one-time: load + convert weights [3 gates][32 units][512] into LDS ----
  const float* wd = whh + (long)d * (GG * HH);
  for (int idx = tid; idx < 96 * 64; idx += 256) {
    int r = idx >> 6;               // 0..95
    int c = (idx & 63) << 3;        // 0..504 step 8
    int gate = r >> 5, u2 = r & 31;
    const float* src = &wd[(long)(gate * HH + U0 + u2) * HH + c];
    float4 a = *(const float4*)&src[0];
    float4 b = *(const float4*)&src[4];
    half8 o;
    o[0] = (__fp16)a.x; o[1] = (__fp16)a.y; o[2] = (__fp16)a.z; o[3] = (__fp16)a.w;
    o[4] = (__fp16)b.x; o[5] = (__fp16)b.y; o[6] = (__fp16)b.z; o[7] = (__fp16)b.w;
    *(half8*)&Wl[r][c] = o;
  }
  __syncthreads();

  // ---- hoist this wave's weight fragments into registers: 48 x half8 ----
  half8 wr_[16], wz_[16], wn_[16];
#pragma unroll
  for (int kk = 0; kk < 16; kk++) {
    const int kcol = (kk << 5) + (quad << 3);
    wr_[kk] = *(const half8*)&Wl[ul][kcol];
    wz_[kk] = *(const half8*)&Wl[32 + ul][kcol];
    wn_[kk] = *(const half8*)&Wl[64 + ul][kcol];
  }

  const float bhr = bhh[d * GG + U0 + ul];
  const float bhz = bhh[d * GG + HH + U0 + ul];
  const float bhn = bhh[d * GG + 2 * HH + U0 + ul];

  // consumer per-lane ULL index within a 16KB hx block (per kk: +kk*128)
  const int cidx = ((quad >> 1) << 6) + (nsub << 2) + ((quad & 1) << 1);
  // producer per-lane ULL index: elem = uo*512 + ut*256 + r*16 + c4
  const int pr = lane & 15, pc4 = (lane >> 4) << 2;
  const int pidx = (uo << 7) + (ut << 6) + (pr << 2) + (pc4 >> 2);

  float hprev[4] = {0.f, 0.f, 0.f, 0.f};

  for (int s = 0; s < TLEN; s++) {
    const int tt = d ? (TLEN - 1 - s) : s;
    // prefetch xp for this step (overlaps the hx spin below)
    float xr[4], xz[4], xn[4];
    {
      const __fp16* xb0 = xp + (long)(tt * BB) * NN + d * GG + U0 + ul;
#pragma unroll
      for (int i = 0; i < 4; i++) {
        const __fp16* xb = xb0 + (long)(bq + (quad << 2) + i) * NN;
        xr[i] = (float)xb[0];
        xz[i] = (float)xb[HH];
        xn[i] = (float)xb[2 * HH];
      }
    }
    floatx4 ar0 = {0.f, 0.f, 0.f, 0.f}, ar1 = ar0, az0 = ar0, az1 = ar0, an0 = ar0, an1 = ar0;
    if (s > 0) {
      const int pt = d ? (tt + 1) : (tt - 1);
      const unsigned long long* hx8 =
          (const unsigned long long*)(hx + ((((long)pt * 2 + d) * 2 + g) * 2 + mb) * 8192);
      // data-as-flag spin: unconditional full 32-load rounds (branch-free,
      // fully coalesced); rounds beyond the first are rare in equilibrium
      hpack u[16];
      int bad;
      do {
#pragma unroll
        for (int kk = 0; kk < 16; kk++) {
          u[kk].u[0] = __hip_atomic_load(&hx8[kk * 128 + cidx], __ATOMIC_RELAXED, __HIP_MEMORY_SCOPE_AGENT);
          u[kk].u[1] = __hip_atomic_load(&hx8[kk * 128 + cidx + 1], __ATOMIC_RELAXED, __HIP_MEMORY_SCOPE_AGENT);
        }
        bad = 0;
#pragma unroll
        for (int kk = 0; kk < 16; kk++)
          bad |= (u[kk].u[0] == SENT) | (u[kk].u[1] == SENT);
      } while (__any(bad));
      // 6 accumulator chains (8-deep each) — halves exposed MFMA latency
#pragma unroll
      for (int kk = 0; kk < 16; kk += 2) {
        ar0 = __builtin_amdgcn_mfma_f32_16x16x32_f16(u[kk].v, wr_[kk], ar0, 0, 0, 0);
        az0 = __builtin_amdgcn_mfma_f32_16x16x32_f16(u[kk].v, wz_[kk], az0, 0, 0, 0);
        an0 = __builtin_amdgcn_mfma_f32_16x16x32_f16(u[kk].v, wn_[kk], an0, 0, 0, 0);
        ar1 = __builtin_amdgcn_mfma_f32_16x16x32_f16(u[kk + 1].v, wr_[kk + 1], ar1, 0, 0, 0);
        az1 = __builtin_amdgcn_mfma_f32_16x16x32_f16(u[kk + 1].v, wz_[kk + 1], az1, 0, 0, 0);
        an1 = __builtin_amdgcn_mfma_f32_16x16x32_f16(u[kk + 1].v, wn_[kk + 1], an1, 0, 0, 0);
      }
    }
    // epilogue: gates in fp32; h_old in registers (same lane wrote it)
#pragma unroll
    for (int i = 0; i < 4; i++) {
      float grv = ar0[i] + ar1[i] + xr[i] + bhr;
      float gzv = az0[i] + az1[i] + xz[i] + bhz;
      float gnv = an0[i] + an1[i] + bhn;        // recurrent part of n-gate (+b_hh)
      float rg = 1.f / (1.f + __expf(-grv));
      float zg = 1.f / (1.f + __expf(-gzv));
      float ex = __expf(2.f * (xn[i] + rg * gnv));
      float ng = 1.f - 2.f / (ex + 1.f);        // tanh
      float hv = (1.f - zg) * ng + zg * hprev[i];
      hprev[i] = hv;
      hst[wv][(quad << 2) + i][nsub] = (__fp16)hv;   // wave-local transpose stage
    }
    // COMPILER barrier: keep all hst DS writes before the DS read below
    // (DS pipe is in-order per wave; only IR ordering must be pinned).
    asm volatile("" ::: "memory");
    // publish own 16x16 tile: hx (exchange) via 8B atomic store — the wave's
    // 64 lanes cover 512 consecutive bytes; hout (standard layout) via plain
    // cached store, consumed only after kernel end.
    {
      hpack4 pk;
      pk.h4 = *(const half4*)&hst[wv][pr][pc4];
      unsigned long long* hxw =
          (unsigned long long*)(hx + ((((long)tt * 2 + d) * 2 + g) * 2 + mb) * 8192);
      __hip_atomic_store(&hxw[pidx], pk.u, __ATOMIC_RELAXED, __HIP_MEMORY_SCOPE_AGENT);
      *(half4*)&hout[(long)(tt * BB + (g << 5) + (mb << 4) + pr) * 1024 +
                     d * HH + U0 + (ut << 4) + pc4] = pk.h4;
    }
  }
}

// ---- max-pool over T ----
__global__ __launch_bounds__(256) void g2_pool(const __fp16* __restrict__ h1,
                                               float* __restrict__ pooled) {
  int b = blockIdx.x;
  int j0 = threadIdx.x * 4;
  float m[4] = {-3e38f, -3e38f, -3e38f, -3e38f};
  const __fp16* p = h1 + b * 1024 + j0;
  for (int t = 0; t < TLEN; t++) {
    half4 v = *(const half4*)(p + (long)t * BB * 1024);
#pragma unroll
    for (int q = 0; q < 4; q++) m[q] = fmaxf(m[q], (float)v[q]);
  }
  float* o = pooled + b * 1024 + j0;
#pragma unroll
  for (int q = 0; q < 4; q++) o[q] = m[q];
}

// ---- classifier head (all fp32) ----
__global__ __launch_bounds__(128) void g2_head(const float* __restrict__ pooled,
                                               const float* __restrict__ w1,
                                               const float* __restrict__ b1,
                                               const float* __restrict__ w2,
                                               const float* __restrict__ b2,
                                               float* __restrict__ out) {
  __shared__ float pl[1024];
  __shared__ float hid[128];
  int b = blockIdx.x, j = threadIdx.x;
  for (int k = j; k < 1024; k += 128) pl[k] = pooled[b * 1024 + k];
  __syncthreads();
  float acc = b1[j];
  const float* wr = w1 + (long)j * 1024;
  for (int k = 0; k < 1024; k += 4) {
    float4 w = *(const float4*)&wr[k];
    acc += pl[k] * w.x + pl[k + 1] * w.y + pl[k + 2] * w.z + pl[k + 3] * w.w;
  }
  hid[j] = fmaxf(acc, 0.f);
  __syncthreads();
  if (j < 2) {
    float a = b2[j];
    for (int k = 0; k < 128; k++) a += hid[k] * w2[j * 128 + k];
    out[b * 2 + j] = a;
  }
}

extern "C" void kernel_launch(void* const* d_in, const int* in_sizes, int n_in,
                              void* d_out, int out_size, void* d_ws, size_t ws_size,
                              hipStream_t stream) {
  (void)in_sizes; (void)n_in; (void)out_size; (void)ws_size;
  const int* x = (const int*)d_in[0];
  const float* emb = (const float*)d_in[1];
  const float* w_ih0 = (const float*)d_in[2];
  const float* w_hh0 = (const float*)d_in[3];
  const float* b_ih0 = (const float*)d_in[4];
  const float* b_hh0 = (const float*)d_in[5];
  const float* w_ih1 = (const float*)d_in[6];
  const float* w_hh1 = (const float*)d_in[7];
  const float* b_ih1 = (const float*)d_in[8];
  const float* b_hh1 = (const float*)d_in[9];
  const float* w1 = (const float*)d_in[10];
  const float* b1 = (const float*)d_in[11];
  const float* w2 = (const float*)d_in[12];
  const float* b2 = (const float*)d_in[13];

  // ---- workspace layout (total <= 186,785,792 B, unchanged) ----
  // hx exchange buffers ALIAS the dead h-region of the other layer:
  //   rnn0: hout=h0, hx=h1 region (h1 dead until rnn1 writes it)
  //   rnn1: hout=h1, hx=h0 region (h0 dead after gemm1 consumed it)
  char* ws = (char*)d_ws;
  __fp16* xp = (__fp16*)(ws + 0);                  // 16384*3072*2 = 100,663,296
  __fp16* h0 = (__fp16*)(ws + 100663296);          // 16384*1024*2 =  33,554,432
  __fp16* h1 = (__fp16*)(ws + 134217728);          //                 33,554,432
  __fp16* e_pad = (__fp16*)(ws + 167772160);       // 16384*320*2  =  10,485,760
  __fp16* w0p = (__fp16*)(ws + 178257920);         // 3072*320*2   =   1,966,080
  __fp16* w1c = (__fp16*)(ws + 180224000);         // 3072*1024*2  =   6,291,456
  float* pooled = (float*)(ws + 186515456);        // 64*1024*4    =     262,144

  // sentinel-fill hx for rnn0 (= h1 region): 0xFFFF per fp16 = -NaN
  (void)hipMemsetAsync(h1, 0xFF, 33554432, stream);
  g2_prep<<<7616, 256, 0, stream>>>(x, emb, e_pad, w_ih0, w0p, w_ih1, w1c);
  g2_gemm<<<3072, 256, 0, stream>>>(e_pad, w0p, b_ih0, xp, MM, NN, EPAD);
  g2_rnn<<<64, 256, 0, stream>>>(w_hh0, b_hh0, xp, h0, h1);
  g2_gemm<<<3072, 256, 0, stream>>>(h0, w1c, b_ih1, xp, MM, NN, 1024);
  // h0 now dead -> becomes hx for rnn1 (stream-ordered after gemm consumed it)
  (void)hipMemsetAsync(h0, 0xFF, 33554432, stream);
  g2_rnn<<<64, 256, 0, stream>>>(w_hh1, b_hh1, xp, h1, h0);
  g2_pool<<<64, 256, 0, stream>>>(h1, pooled);
  g2_head<<<64, 128, 0, stream>>>(pooled, w1, b1, w2, b2, (float*)d_out);
}